// Round 1
// baseline (304.127 us; speedup 1.0000x reference)
//
#include <hip/hip_runtime.h>
#include <math.h>

// WavefunctionEmbedding: out[b,i,2k+0/1] = sum_j amp(b,i,j) * {cos,sin}(wn_k * r_ij)
//   r_ij = sqrt(|c_i - c_j|^2 + 1e-12), amp = 1/(4*pi*max(r,1e-6)), 0 if j==i or padded.
// Fixed problem: B=2, N=1536, K=256 (d_model=512).
//
// Key idea: wn_k = 2*pi/lambda, and gfx950 v_sin_f32/v_cos_f32 take input in
// REVOLUTIONS (D = sin(S0*2pi)). So cos(wn*r) = hw_cos(fract(r * wn/(2pi))):
// one v_mul + v_fract + raw quarter-rate trans op, no libm range reduction.

#define N_FIXED 1536

__global__ __launch_bounds__(256) void WavefunctionEmbedding_28278064676910_kernel(
    const float* __restrict__ coords,          // [B,N,3]
    const unsigned char* __restrict__ mask,    // [B,N] bool (True = padded)
    const float* __restrict__ wavenumbers,     // [K]
    float* __restrict__ out,                   // [B,N,2K]
    int N, int K)
{
    __shared__ float2 pairs[N_FIXED];          // {r, amp} per source j  (12 KB)

    const int row = blockIdx.x;                // b*N + i
    const int b   = row / N;
    const int i   = row - b * N;
    const int t   = threadIdx.x;

    const float* crow = coords + (size_t)b * N * 3;
    const float xi = crow[i * 3 + 0];
    const float yi = crow[i * 3 + 1];
    const float zi = crow[i * 3 + 2];
    const unsigned char* mrow = mask + (size_t)b * N;

    // Phase 1: cooperative r/amp row into LDS.
    for (int j = t; j < N; j += blockDim.x) {
        float dx = crow[j * 3 + 0] - xi;
        float dy = crow[j * 3 + 1] - yi;
        float dz = crow[j * 3 + 2] - zi;
        float d2 = fmaf(dx, dx, fmaf(dy, dy, fmaf(dz, dz, 1e-12f)));
        float r  = sqrtf(d2);
        float amp = 0.07957747154594767f / fmaxf(r, 1e-6f);   // 1/(4*pi*r)
        if (j == i || mrow[j]) amp = 0.0f;
        pairs[j] = make_float2(r, amp);
    }
    __syncthreads();

    // Phase 2: thread t owns wavenumber k = t.
    const int k = t;
    const float f = wavenumbers[k] * 0.15915494309189535f;    // wn/(2*pi) = 1/lambda
    float re = 0.0f, im = 0.0f;
    #pragma unroll 4
    for (int j = 0; j < N; ++j) {
        float2 p = pairs[j];                                   // ds_read_b64, broadcast
        float x  = __builtin_amdgcn_fractf(p.x * f);           // revolutions in [0,1)
        float c  = __builtin_amdgcn_cosf(x);                   // v_cos_f32
        float s  = __builtin_amdgcn_sinf(x);                   // v_sin_f32
        re = fmaf(c, p.y, re);
        im = fmaf(s, p.y, im);
    }

    float2* orow = (float2*)out + (size_t)row * K;
    orow[k] = make_float2(re, im);                             // out[b,i,2k], out[b,i,2k+1]
}

extern "C" void kernel_launch(void* const* d_in, const int* in_sizes, int n_in,
                              void* d_out, int out_size, void* d_ws, size_t ws_size,
                              hipStream_t stream) {
    const float* coords          = (const float*)d_in[0];
    const unsigned char* mask    = (const unsigned char*)d_in[1];
    const float* wavenumbers     = (const float*)d_in[2];
    float* out                   = (float*)d_out;

    const int K  = in_sizes[2];        // 256
    const int N  = N_FIXED;            // 1536
    const int BN = in_sizes[0] / 3;    // B*N = 3072

    WavefunctionEmbedding_28278064676910_kernel<<<BN, K, 0, stream>>>(
        coords, mask, wavenumbers, out, N, K);
}

// Round 2
// 193.086 us; speedup vs baseline: 1.5751x; 1.5751x over previous
//
#include <hip/hip_runtime.h>
#include <math.h>

// WavefunctionEmbedding, histogram-factorized:
//   out[b,i,2k+0/1] = sum_j amp_ij * {cos,sin}(wn_k * r_ij)
// Since the pair sum is a 1-D integral over r, scatter amp into a per-row
// radial histogram (cubic Lagrange deposit onto Q=256 nodes), then contract
// with a precomputed [Q+4, 2K] cos/sin table: out = H x W  (small GEMM).
// Trans ops drop from 2.4e9 (2 per pair-k) to 1.3e5 (table only).
//
// Pipeline (all on stream, ws-mediated, graph-capture safe):
//   k1: Rmax = 2*max|c| over all points -> h = Rmax/Q, 1/h   (ws scalars)
//   k2: W[a][2k,2k+1] = cos/sin(wn_k * (a-1)*h), a in [0,260)
//   k3: per row i: LDS histogram over j (4-tap cubic weights, ds fp32 atomics)
//   k4: out = H x W, row-tiled x12 so W stays L2-resident.

#define N_FIXED 1536
#define K_FIXED 256
#define QBINS   256
#define QG      (QBINS + 4)     // ghost nodes at -1 and Q+1, Q+2
#define RT      12              // rows per GEMM block (256 blocks * 12 = 3072)

// ---------------- fallback: direct kernel (round-1, known-good) ------------
__global__ __launch_bounds__(256) void wf_direct_kernel(
    const float* __restrict__ coords, const unsigned char* __restrict__ mask,
    const float* __restrict__ wavenumbers, float* __restrict__ out, int N, int K)
{
    __shared__ float2 pairs[N_FIXED];
    const int row = blockIdx.x;
    const int b   = row / N;
    const int i   = row - b * N;
    const int t   = threadIdx.x;
    const float* crow = coords + (size_t)b * N * 3;
    const float xi = crow[i*3+0], yi = crow[i*3+1], zi = crow[i*3+2];
    const unsigned char* mrow = mask + (size_t)b * N;
    for (int j = t; j < N; j += blockDim.x) {
        float dx = crow[j*3+0]-xi, dy = crow[j*3+1]-yi, dz = crow[j*3+2]-zi;
        float d2 = fmaf(dx,dx, fmaf(dy,dy, fmaf(dz,dz, 1e-12f)));
        float r  = sqrtf(d2);
        float amp = 0.07957747154594767f / fmaxf(r, 1e-6f);
        if (j == i || mrow[j]) amp = 0.0f;
        pairs[j] = make_float2(r, amp);
    }
    __syncthreads();
    const int k = t;
    const float f = wavenumbers[k] * 0.15915494309189535f;
    float re = 0.0f, im = 0.0f;
    #pragma unroll 4
    for (int j = 0; j < N; ++j) {
        float2 p = pairs[j];
        float x  = __builtin_amdgcn_fractf(p.x * f);
        float c  = __builtin_amdgcn_cosf(x);
        float s  = __builtin_amdgcn_sinf(x);
        re = fmaf(c, p.y, re);
        im = fmaf(s, p.y, im);
    }
    float2* orow = (float2*)out + (size_t)row * K;
    orow[k] = make_float2(re, im);
}

// ---------------- k1: grid scale (Rmax -> h, inv_h) ------------------------
__global__ __launch_bounds__(1024) void wf_scale_kernel(
    const float* __restrict__ coords, int n_pts, float* __restrict__ ws_f)
{
    __shared__ float wmax[16];
    const int t = threadIdx.x;
    float m = 0.0f;
    for (int p = t; p < n_pts; p += 1024) {
        float x = coords[3*p], y = coords[3*p+1], z = coords[3*p+2];
        m = fmaxf(m, fmaf(x,x, fmaf(y,y, z*z)));
    }
    #pragma unroll
    for (int off = 32; off >= 1; off >>= 1)
        m = fmaxf(m, __shfl_down(m, off, 64));
    if ((t & 63) == 0) wmax[t >> 6] = m;
    __syncthreads();
    if (t == 0) {
        float mm = 0.0f;
        #pragma unroll
        for (int w = 0; w < 16; ++w) mm = fmaxf(mm, wmax[w]);
        float rmax = 2.0005f * sqrtf(mm) + 1e-3f;   // r_ij <= |c_i|+|c_j| <= 2 max|c|
        float h = rmax / (float)QBINS;
        ws_f[0] = h;
        ws_f[1] = 1.0f / h;
    }
}

// ---------------- k2: cos/sin table W[a][2k..2k+1] -------------------------
__global__ __launch_bounds__(256) void wf_table_kernel(
    const float* __restrict__ wavenumbers, const float* __restrict__ ws_f,
    float* __restrict__ W)
{
    const int a = blockIdx.x;            // node index, r = (a-1)*h
    const int k = threadIdx.x;
    const float h = ws_f[0];
    const float r = ((float)a - 1.0f) * h;
    const float f = wavenumbers[k] * 0.15915494309189535f;   // revolutions/unit r
    float x = __builtin_amdgcn_fractf(f * r);
    float c = __builtin_amdgcn_cosf(x);
    float s = __builtin_amdgcn_sinf(x);
    float2* Wrow = (float2*)(W + (size_t)a * 2 * K_FIXED);
    Wrow[k] = make_float2(c, s);
}

// ---------------- k3: per-row radial histogram -----------------------------
__global__ __launch_bounds__(256) void wf_hist_kernel(
    const float* __restrict__ coords, const unsigned char* __restrict__ mask,
    const float* __restrict__ ws_f, float* __restrict__ H, int N)
{
    __shared__ float lds_c[N_FIXED * 3];   // 18 KB
    __shared__ float hist[QG];             // 1 KB

    const int row = blockIdx.x;
    const int b   = row / N;
    const int i   = row - b * N;
    const int t   = threadIdx.x;
    const float inv_h = ws_f[1];

    const float* crow = coords + (size_t)b * N * 3;
    const unsigned char* mrow = mask + (size_t)b * N;

    // stage coords row (float4 x 1152) + zero hist
    const float4* src4 = (const float4*)crow;
    float4* dst4 = (float4*)lds_c;
    for (int v = t; v < (N_FIXED * 3) / 4; v += 256) dst4[v] = src4[v];
    for (int a = t; a < QG; a += 256) hist[a] = 0.0f;
    __syncthreads();

    const float xi = lds_c[3*i], yi = lds_c[3*i+1], zi = lds_c[3*i+2];

    #pragma unroll
    for (int s = 0; s < N_FIXED / 256; ++s) {
        int j = t + 256 * s;
        float dx = lds_c[3*j]   - xi;
        float dy = lds_c[3*j+1] - yi;
        float dz = lds_c[3*j+2] - zi;
        float d2 = fmaf(dx,dx, fmaf(dy,dy, fmaf(dz,dz, 1e-12f)));
        float r  = sqrtf(d2);
        float amp = 0.07957747154594767f / fmaxf(r, 1e-6f);
        if (j == i || mrow[j]) amp = 0.0f;

        float u  = r * inv_h;
        float qf = floorf(u);
        int   q0 = (int)qf;
        q0 = q0 < 0 ? 0 : (q0 > QBINS ? QBINS : q0);
        float tt = u - qf;
        // Lagrange cubic through nodes {-1,0,1,2} at offset tt in [0,1)
        float tm1 = tt + 1.0f, t1 = tt - 1.0f, t2 = tt - 2.0f;
        float w0 = -tt * t1 * t2 * (1.0f/6.0f);
        float w1 =  tm1 * t1 * t2 * 0.5f;
        float w2 = -tm1 * tt * t2 * 0.5f;
        float w3 =  tm1 * tt * t1 * (1.0f/6.0f);
        atomicAdd(&hist[q0    ], amp * w0);
        atomicAdd(&hist[q0 + 1], amp * w1);
        atomicAdd(&hist[q0 + 2], amp * w2);
        atomicAdd(&hist[q0 + 3], amp * w3);
    }
    __syncthreads();

    float* Hrow = H + (size_t)row * QG;
    for (int a = t; a < QG; a += 256) Hrow[a] = hist[a];
}

// ---------------- k4: out = H x W  (row-tiled GEMM) ------------------------
__global__ __launch_bounds__(256) void wf_gemm_kernel(
    const float* __restrict__ H, const float* __restrict__ W,
    float* __restrict__ out)
{
    __shared__ float Hs[QG * RT];          // [q][r], rows of 12 floats (48 B, 16B-aligned)
    const int i0 = blockIdx.x * RT;
    const int t  = threadIdx.x;            // = k-pair index

    for (int idx = t; idx < RT * QG; idx += 256) {
        int r = idx / QG;
        int q = idx - r * QG;
        Hs[q * RT + r] = H[(size_t)(i0 + r) * QG + q];
    }
    __syncthreads();

    float2 acc[RT];
    #pragma unroll
    for (int r = 0; r < RT; ++r) acc[r] = make_float2(0.0f, 0.0f);

    #pragma unroll 4
    for (int q = 0; q < QG; ++q) {
        float2 w = ((const float2*)(W + (size_t)q * 2 * K_FIXED))[t];
        const float4* hq = (const float4*)&Hs[q * RT];
        float4 h0 = hq[0], h1 = hq[1], h2 = hq[2];   // broadcast LDS reads
        const float hv[RT] = {h0.x,h0.y,h0.z,h0.w, h1.x,h1.y,h1.z,h1.w,
                              h2.x,h2.y,h2.z,h2.w};
        #pragma unroll
        for (int r = 0; r < RT; ++r) {
            acc[r].x = fmaf(hv[r], w.x, acc[r].x);
            acc[r].y = fmaf(hv[r], w.y, acc[r].y);
        }
    }

    #pragma unroll
    for (int r = 0; r < RT; ++r)
        ((float2*)out)[(size_t)(i0 + r) * K_FIXED + t] = acc[r];
}

extern "C" void kernel_launch(void* const* d_in, const int* in_sizes, int n_in,
                              void* d_out, int out_size, void* d_ws, size_t ws_size,
                              hipStream_t stream) {
    const float* coords          = (const float*)d_in[0];
    const unsigned char* mask    = (const unsigned char*)d_in[1];
    const float* wavenumbers     = (const float*)d_in[2];
    float* out                   = (float*)d_out;

    const int K  = in_sizes[2];
    const int BN = in_sizes[0] / 3;        // B*N
    const int N  = N_FIXED;

    // ws layout (floats): [0]=h [1]=inv_h | W at +16 (QG*2K) | H (BN*QG)
    const size_t W_off = 16;
    const size_t H_off = W_off + (size_t)QG * 2 * K_FIXED;
    const size_t need  = (H_off + (size_t)BN * QG) * sizeof(float);

    if (K != K_FIXED || BN % N != 0 || ws_size < need) {
        wf_direct_kernel<<<BN, K, 0, stream>>>(coords, mask, wavenumbers, out, N, K);
        return;
    }

    float* ws_f = (float*)d_ws;
    float* W    = ws_f + W_off;
    float* H    = ws_f + H_off;

    wf_scale_kernel<<<1, 1024, 0, stream>>>(coords, BN, ws_f);
    wf_table_kernel<<<QG, K_FIXED, 0, stream>>>(wavenumbers, ws_f, W);
    wf_hist_kernel <<<BN, 256, 0, stream>>>(coords, mask, ws_f, H, N);
    wf_gemm_kernel <<<BN / RT, 256, 0, stream>>>(H, W, out);
}

// Round 3
// 98.072 us; speedup vs baseline: 3.1011x; 1.9688x over previous
//
#include <hip/hip_runtime.h>
#include <math.h>

// WavefunctionEmbedding, histogram-factorized:
//   out[b,i,2k+0/1] = sum_j amp_ij * {cos,sin}(wn_k * r_ij)
// Scatter amp into a per-row radial histogram (cubic Lagrange deposit onto
// Q=256 nodes), then contract with a precomputed [Q+4, 2K] cos/sin table:
// out = H x W (small GEMM). Trans ops: 2.4e9 -> 1.3e5.
//
// R3 changes vs R2:
//  - hist: fp32 LDS atomicAdd compiled to a CAS retry loop (VALUBusy 8.6%,
//    102 us). Replaced with FIXED-POINT int32 LDS atomics (native ds_add_u32,
//    fire-and-forget, deterministic). Scale 2^22: deposits <= ~2e6, bin sums
//    <= ~1e8, int32-safe; quantization noise ~1e-7/deposit, negligible.
//  - hist: dropped 18 KB coords LDS staging (threads read only their own j's;
//    L1/L2 serve them) -- one less barrier, LDS 19.5 KB -> ~1 KB.
//  - gemm: RT 12 -> 6 (512 blocks, 2 blocks/CU) for latency hiding.

#define N_FIXED 1536
#define K_FIXED 256
#define QBINS   256
#define QG      (QBINS + 4)     // ghost nodes at -1 and Q+1, Q+2
#define RT      6               // rows per GEMM block (512 blocks * 6 = 3072)
#define FPSCALE 4194304.0f      // 2^22 fixed-point scale for hist deposits

// ---------------- fallback: direct kernel (round-1, known-good) ------------
__global__ __launch_bounds__(256) void wf_direct_kernel(
    const float* __restrict__ coords, const unsigned char* __restrict__ mask,
    const float* __restrict__ wavenumbers, float* __restrict__ out, int N, int K)
{
    __shared__ float2 pairs[N_FIXED];
    const int row = blockIdx.x;
    const int b   = row / N;
    const int i   = row - b * N;
    const int t   = threadIdx.x;
    const float* crow = coords + (size_t)b * N * 3;
    const float xi = crow[i*3+0], yi = crow[i*3+1], zi = crow[i*3+2];
    const unsigned char* mrow = mask + (size_t)b * N;
    for (int j = t; j < N; j += blockDim.x) {
        float dx = crow[j*3+0]-xi, dy = crow[j*3+1]-yi, dz = crow[j*3+2]-zi;
        float d2 = fmaf(dx,dx, fmaf(dy,dy, fmaf(dz,dz, 1e-12f)));
        float r  = sqrtf(d2);
        float amp = 0.07957747154594767f / fmaxf(r, 1e-6f);
        if (j == i || mrow[j]) amp = 0.0f;
        pairs[j] = make_float2(r, amp);
    }
    __syncthreads();
    const int k = t;
    const float f = wavenumbers[k] * 0.15915494309189535f;
    float re = 0.0f, im = 0.0f;
    #pragma unroll 4
    for (int j = 0; j < N; ++j) {
        float2 p = pairs[j];
        float x  = __builtin_amdgcn_fractf(p.x * f);
        float c  = __builtin_amdgcn_cosf(x);
        float s  = __builtin_amdgcn_sinf(x);
        re = fmaf(c, p.y, re);
        im = fmaf(s, p.y, im);
    }
    float2* orow = (float2*)out + (size_t)row * K;
    orow[k] = make_float2(re, im);
}

// ---------------- k1: grid scale (Rmax -> h, inv_h) ------------------------
__global__ __launch_bounds__(1024) void wf_scale_kernel(
    const float* __restrict__ coords, int n_pts, float* __restrict__ ws_f)
{
    __shared__ float wmax[16];
    const int t = threadIdx.x;
    float m = 0.0f;
    for (int p = t; p < n_pts; p += 1024) {
        float x = coords[3*p], y = coords[3*p+1], z = coords[3*p+2];
        m = fmaxf(m, fmaf(x,x, fmaf(y,y, z*z)));
    }
    #pragma unroll
    for (int off = 32; off >= 1; off >>= 1)
        m = fmaxf(m, __shfl_down(m, off, 64));
    if ((t & 63) == 0) wmax[t >> 6] = m;
    __syncthreads();
    if (t == 0) {
        float mm = 0.0f;
        #pragma unroll
        for (int w = 0; w < 16; ++w) mm = fmaxf(mm, wmax[w]);
        float rmax = 2.0005f * sqrtf(mm) + 1e-3f;   // r_ij <= 2 max|c|
        float h = rmax / (float)QBINS;
        ws_f[0] = h;
        ws_f[1] = 1.0f / h;
    }
}

// ---------------- k2: cos/sin table W[a][2k..2k+1] -------------------------
__global__ __launch_bounds__(256) void wf_table_kernel(
    const float* __restrict__ wavenumbers, const float* __restrict__ ws_f,
    float* __restrict__ W)
{
    const int a = blockIdx.x;            // node index, r = (a-1)*h
    const int k = threadIdx.x;
    const float h = ws_f[0];
    const float r = ((float)a - 1.0f) * h;
    const float f = wavenumbers[k] * 0.15915494309189535f;   // revolutions/unit r
    float x = __builtin_amdgcn_fractf(f * r);
    float c = __builtin_amdgcn_cosf(x);
    float s = __builtin_amdgcn_sinf(x);
    float2* Wrow = (float2*)(W + (size_t)a * 2 * K_FIXED);
    Wrow[k] = make_float2(c, s);
}

// ---------------- k3: per-row radial histogram (int fixed-point) -----------
__global__ __launch_bounds__(256) void wf_hist_kernel(
    const float* __restrict__ coords, const unsigned char* __restrict__ mask,
    const float* __restrict__ ws_f, float* __restrict__ H, int N)
{
    __shared__ int hist[QG];               // ~1 KB

    const int row = blockIdx.x;
    const int b   = row / N;
    const int i   = row - b * N;
    const int t   = threadIdx.x;
    const float inv_h = ws_f[1];

    const float* crow = coords + (size_t)b * N * 3;
    const unsigned char* mrow = mask + (size_t)b * N;

    for (int a = t; a < QG; a += 256) hist[a] = 0;
    __syncthreads();

    const float xi = crow[3*i], yi = crow[3*i+1], zi = crow[3*i+2];

    #pragma unroll
    for (int s = 0; s < N_FIXED / 256; ++s) {
        int j = t + 256 * s;
        float dx = crow[3*j]   - xi;
        float dy = crow[3*j+1] - yi;
        float dz = crow[3*j+2] - zi;
        float d2 = fmaf(dx,dx, fmaf(dy,dy, fmaf(dz,dz, 1e-12f)));
        float r  = sqrtf(d2);
        float amp = 0.07957747154594767f / fmaxf(r, 1e-6f);
        if (j == i || mrow[j]) amp = 0.0f;

        float u  = r * inv_h;
        float qf = floorf(u);
        int   q0 = (int)qf;
        q0 = q0 < 0 ? 0 : (q0 > QBINS ? QBINS : q0);
        float tt = u - qf;
        // Lagrange cubic through nodes {-1,0,1,2} at offset tt in [0,1)
        float as  = amp * FPSCALE;
        float tm1 = tt + 1.0f, t1 = tt - 1.0f, t2 = tt - 2.0f;
        float w0 = -tt * t1 * t2 * (1.0f/6.0f) * as;
        float w1 =  tm1 * t1 * t2 * 0.5f * as;
        float w2 = -tm1 * tt * t2 * 0.5f * as;
        float w3 =  tm1 * tt * t1 * (1.0f/6.0f) * as;
        atomicAdd(&hist[q0    ], __float2int_rn(w0));   // native ds_add_u32
        atomicAdd(&hist[q0 + 1], __float2int_rn(w1));
        atomicAdd(&hist[q0 + 2], __float2int_rn(w2));
        atomicAdd(&hist[q0 + 3], __float2int_rn(w3));
    }
    __syncthreads();

    float* Hrow = H + (size_t)row * QG;
    const float invS = 1.0f / FPSCALE;
    for (int a = t; a < QG; a += 256) Hrow[a] = (float)hist[a] * invS;
}

// ---------------- k4: out = H x W  (row-tiled GEMM) ------------------------
__global__ __launch_bounds__(256) void wf_gemm_kernel(
    const float* __restrict__ H, const float* __restrict__ W,
    float* __restrict__ out)
{
    __shared__ float Hs[QG * RT];          // [q][r]
    const int i0 = blockIdx.x * RT;
    const int t  = threadIdx.x;            // = k-pair index

    for (int idx = t; idx < RT * QG; idx += 256) {
        int r = idx / QG;
        int q = idx - r * QG;
        Hs[q * RT + r] = H[(size_t)(i0 + r) * QG + q];
    }
    __syncthreads();

    float2 acc[RT];
    #pragma unroll
    for (int r = 0; r < RT; ++r) acc[r] = make_float2(0.0f, 0.0f);

    #pragma unroll 4
    for (int q = 0; q < QG; ++q) {
        float2 w = ((const float2*)(W + (size_t)q * 2 * K_FIXED))[t];
        #pragma unroll
        for (int r = 0; r < RT; ++r) {
            float hv = Hs[q * RT + r];     // broadcast LDS read
            acc[r].x = fmaf(hv, w.x, acc[r].x);
            acc[r].y = fmaf(hv, w.y, acc[r].y);
        }
    }

    #pragma unroll
    for (int r = 0; r < RT; ++r)
        ((float2*)out)[(size_t)(i0 + r) * K_FIXED + t] = acc[r];
}

extern "C" void kernel_launch(void* const* d_in, const int* in_sizes, int n_in,
                              void* d_out, int out_size, void* d_ws, size_t ws_size,
                              hipStream_t stream) {
    const float* coords          = (const float*)d_in[0];
    const unsigned char* mask    = (const unsigned char*)d_in[1];
    const float* wavenumbers     = (const float*)d_in[2];
    float* out                   = (float*)d_out;

    const int K  = in_sizes[2];
    const int BN = in_sizes[0] / 3;        // B*N
    const int N  = N_FIXED;

    // ws layout (floats): [0]=h [1]=inv_h | W at +16 (QG*2K) | H (BN*QG)
    const size_t W_off = 16;
    const size_t H_off = W_off + (size_t)QG * 2 * K_FIXED;
    const size_t need  = (H_off + (size_t)BN * QG) * sizeof(float);

    if (K != K_FIXED || BN % N != 0 || (BN % RT) != 0 || ws_size < need) {
        wf_direct_kernel<<<BN, K, 0, stream>>>(coords, mask, wavenumbers, out, N, K);
        return;
    }

    float* ws_f = (float*)d_ws;
    float* W    = ws_f + W_off;
    float* H    = ws_f + H_off;

    wf_scale_kernel<<<1, 1024, 0, stream>>>(coords, BN, ws_f);
    wf_table_kernel<<<QG, K_FIXED, 0, stream>>>(wavenumbers, ws_f, W);
    wf_hist_kernel <<<BN, 256, 0, stream>>>(coords, mask, ws_f, H, N);
    wf_gemm_kernel <<<BN / RT, 256, 0, stream>>>(H, W, out);
}